// Round 10
// baseline (361.032 us; speedup 1.0000x reference)
//
#include <hip/hip_runtime.h>
#include <cstdint>
#include <cstddef>

// ---- problem constants ----
constexpr int B_   = 2;
constexpr int N_   = 2000;
constexpr int M_   = 64;
constexpr int NB_  = N_ + M_;       // 2064
constexpr int C_   = 256;
constexpr int H_   = 64;
constexpr int W_   = 64;
constexpr int RPI  = 512;
constexpr int RTOT = B_ * RPI;      // 1024
constexpr int FG_CAP_ = 128;
constexpr int D_   = C_ * 49;       // 12544
constexpr int FC_  = 1024;
constexpr int OUTC = 401;           // 81 + 320
constexpr int KT1  = D_ / 32;       // 392 k-tiles for FC1
constexpr int KT2  = FC_ / 32;      // 32 k-tiles for FC2/heads
constexpr float IOU_T = 0.5f;

typedef _Float16 f16;
typedef f16   f16x2 __attribute__((ext_vector_type(2)));
typedef f16   f16x8 __attribute__((ext_vector_type(8)));
typedef float f32x4 __attribute__((ext_vector_type(4)));

__device__ __forceinline__ void tile_load16(const void* g, void* l) {
  __builtin_amdgcn_global_load_lds(
      (const __attribute__((address_space(1))) unsigned int*)g,
      (__attribute__((address_space(3))) unsigned int*)l, 16, 0, 0);
}

// ---------------------------------------------------------------------------
// K_TIOU: fused transpose (blocks 0..1023) + IoU fg flags (blocks 1024,1025).
// Both are simple, independent, input-only; disjoint block ranges.
// ---------------------------------------------------------------------------
__global__ __launch_bounds__(256) void k_tiou(
    const float* __restrict__ feat, const float* __restrict__ prop,
    const float* __restrict__ gtb, f16* __restrict__ fT,
    unsigned char* __restrict__ fg, int* __restrict__ cnt) {
  __shared__ __align__(16) char smem[8448];
  int bid = blockIdx.x;
  int t = threadIdx.x;
  if (bid < 1024) {
    float (*tile)[33] = (float(*)[33])smem;  // [64][33] fits 8448? 64*33*4=8448 ✓
    int b = bid >> 9, rem = bid & 511;
    int hw0 = (rem & 127) * 32, c0 = ((rem >> 7) & 3) * 64;
    int tx = t & 31, cr0 = t >> 5;
#pragma unroll
    for (int i = 0; i < 8; ++i) {
      int cr = cr0 + i * 8;
      tile[cr][tx] = feat[((size_t)b * C_ + c0 + cr) * (H_ * W_) + hw0 + tx];
    }
    __syncthreads();
    int c2 = (t & 31) * 2, hr0 = t >> 5;
#pragma unroll
    for (int p = 0; p < 4; ++p) {
      int hr = hr0 + p * 8;
      f16x2 v;
      v[0] = (f16)tile[c2][hr];
      v[1] = (f16)tile[c2 + 1][hr];
      *(f16x2*)(fT + ((size_t)b * (H_ * W_) + hw0 + hr) * C_ + c0 + c2) = v;
    }
  } else {
    float* s_gt   = (float*)smem;            // 1024 B
    float* s_area = (float*)(smem + 1024);   // 256 B
    int*   s_cnt  = (int*)(smem + 1280);
    int b = bid - 1024;
    if (t == 0) *s_cnt = 0;
    s_gt[t] = gtb[(size_t)b * M_ * 4 + t];   // t covers exactly M_*4 = 256
    __syncthreads();
    if (t < M_) {
      float x1 = s_gt[t*4], y1 = s_gt[t*4+1], x2 = s_gt[t*4+2], y2 = s_gt[t*4+3];
      s_area[t] = (x2 - x1) * (y2 - y1);
    }
    __syncthreads();
    int local = 0;
    for (int j = t; j < NB_; j += 256) {
      float bx1, by1, bx2, by2;
      if (j < N_) {
        const float* p = prop + ((size_t)b * N_ + j) * 4;
        bx1 = p[0]; by1 = p[1]; bx2 = p[2]; by2 = p[3];
      } else {
        const float* p = s_gt + (j - N_) * 4;
        bx1 = p[0]; by1 = p[1]; bx2 = p[2]; by2 = p[3];
      }
      float area_p = (bx2 - bx1) * (by2 - by1);
      float best = 0.f;
      for (int g = 0; g < M_; ++g) {
        float lx = fmaxf(s_gt[g*4], bx1),   lyv = fmaxf(s_gt[g*4+1], by1);
        float rx = fminf(s_gt[g*4+2], bx2), ry  = fminf(s_gt[g*4+3], by2);
        float w = fmaxf(rx - lx, 0.f), h = fmaxf(ry - lyv, 0.f);
        float inter = w * h;
        float iou = inter > 0.f ? inter / (s_area[g] + area_p - inter) : 0.f;
        best = fmaxf(best, iou);
      }
      int f = (best >= IOU_T) ? 1 : 0;
      fg[(size_t)b * NB_ + j] = (unsigned char)f;
      local += f;
    }
    atomicAdd(s_cnt, local);
    __syncthreads();
    if (t == 0) cnt[b] = *s_cnt;
  }
}

// ---------------------------------------------------------------------------
// S2: branchless rank via combined u64 key (exact JAX stable tie-break).
// ---------------------------------------------------------------------------
__global__ __launch_bounds__(256) void k_rank(const float* __restrict__ rnd,
                                              const unsigned char* __restrict__ fg,
                                              const int* __restrict__ cnt,
                                              unsigned char* __restrict__ sel) {
  __shared__ unsigned long long s_key[NB_];
  int b = blockIdx.y, t = threadIdx.x;
  for (int j = t; j < NB_; j += 256) {
    float r = rnd[(size_t)b * NB_ + j];
    int f = (int)fg[(size_t)b * NB_ + j];
    float ck = r + 2.0f * (float)f;
    unsigned int ib = __float_as_uint(ck);
    s_key[j] = ((unsigned long long)ib << 11) | (unsigned int)j;
  }
  __syncthreads();
  int j = blockIdx.x * 256 + t;
  int jj = (j < NB_) ? j : 0;
  unsigned long long uj = s_key[jj];
  int rank_all = 0;
  const uint4* kp = (const uint4*)s_key;
#pragma unroll 4
  for (int k2 = 0; k2 < NB_ / 2; ++k2) {
    uint4 v = kp[k2];
    unsigned long long k0 = ((unsigned long long)v.y << 32) | v.x;
    unsigned long long k1 = ((unsigned long long)v.w << 32) | v.z;
    rank_all += (k0 < uj) ? 1 : 0;
    rank_all += (k1 < uj) ? 1 : 0;
  }
  if (j >= NB_) return;
  int fgcnt  = cnt[b];
  int num_fg = min(fgcnt, FG_CAP_);
  int num_bg = min(RPI - num_fg, NB_ - fgcnt);
  int myfg   = (uj >> 11) >= 0x40000000ull ? 1 : 0;
  int rank   = rank_all - (myfg ? (NB_ - fgcnt) : 0);
  int lim    = myfg ? num_fg : num_bg;
  sel[(size_t)b * NB_ + j] =
      (rank < lim) ? (unsigned char)(myfg ? 2 : 1) : (unsigned char)0;
}

// ---------------------------------------------------------------------------
// S3: lax.top_k placement via ballot prefix scan. One wave per image.
// ---------------------------------------------------------------------------
__global__ __launch_bounds__(64) void k_place(const float* __restrict__ prop,
                                              const float* __restrict__ gt,
                                              const int* __restrict__ cnt,
                                              const unsigned char* __restrict__ sel,
                                              float* __restrict__ rois) {
  int b = blockIdx.x, L = threadIdx.x;
  int fgcnt  = cnt[b];
  int num_fg = min(fgcnt, FG_CAP_);
  int num_bg = min(RPI - num_fg, NB_ - fgcnt);
  int S = num_fg + num_bg;
  int t2 = 0, t1 = 0, t0 = 0;
  unsigned long long lt = (L == 0) ? 0ull : ((~0ull) >> (64 - L));
  for (int c = 0; c < (NB_ + 63) / 64; ++c) {
    int j = c * 64 + L;
    int s = (j < NB_) ? (int)sel[(size_t)b * NB_ + j] : -1;
    unsigned long long m2 = __ballot(s == 2);
    unsigned long long m1 = __ballot(s == 1);
    unsigned long long m0 = __ballot(s == 0);
    int pos = -1;
    if (s == 2) {
      pos = t2 + __popcll(m2 & lt);
    } else if (s == 1) {
      pos = num_fg + t1 + __popcll(m1 & lt);
    } else if (s == 0) {
      int p0 = t0 + __popcll(m0 & lt);
      if (S + p0 < RPI) pos = S + p0;
    }
    if (pos >= 0) {
      const float* p = (j < N_) ? (prop + ((size_t)b * N_ + j) * 4)
                                : (gt + ((size_t)b * M_ + (j - N_)) * 4);
      float* o = rois + ((size_t)b * RPI + pos) * 4;
      o[0] = p[0]; o[1] = p[1]; o[2] = p[2]; o[3] = p[3];
    }
    t2 += __popcll(m2); t1 += __popcll(m1); t0 += __popcll(m0);
  }
}

// ---------------------------------------------------------------------------
// K2: ROI align (f16 features) -> A1 fp16 fragment-linear.
// ---------------------------------------------------------------------------
__global__ __launch_bounds__(256) void k_roialign(const f16* __restrict__ fT,
                                                  const float* __restrict__ rois,
                                                  f16* __restrict__ Ahi) {
  __shared__ float sv[8][260];
  __shared__ int   s_off[32][4];
  __shared__ float s_w[32][4];
  int mt = blockIdx.x, bin = blockIdx.y;
  int tid = threadIdx.x;
  int by = bin / 7, bx = bin % 7;
  for (int pass = 0; pass < 2; ++pass) {
    if (tid < 32) {
      int rr = tid >> 2, s = tid & 3;
      int r = mt * 16 + pass * 8 + rr;
      const float* rp = rois + (size_t)r * 4;
      float x1 = rp[0] * 0.0625f - 0.5f;
      float y1 = rp[1] * 0.0625f - 0.5f;
      float x2 = rp[2] * 0.0625f - 0.5f;
      float y2 = rp[3] * 0.0625f - 0.5f;
      float stx = (x2 - x1) * (1.0f / 7.0f);
      float sty = (y2 - y1) * (1.0f / 7.0f);
      int oy = s >> 1, ox = s & 1;
      float xs = x1 + ((float)(2 * bx + ox) + 0.5f) * 0.5f * stx;
      float ys = y1 + ((float)(2 * by + oy) + 0.5f) * 0.5f * sty;
      xs = fminf(fmaxf(xs, 0.f), (float)(W_ - 1));
      ys = fminf(fmaxf(ys, 0.f), (float)(H_ - 1));
      int x0 = (int)floorf(xs), y0 = (int)floorf(ys);
      int x1i = min(x0 + 1, W_ - 1), y1i = min(y0 + 1, H_ - 1);
      float lx = xs - (float)x0, ly = ys - (float)y0;
      int base = (r >> 9) * (H_ * W_ * C_);
      s_off[tid][0] = base + (y0  * W_ + x0 ) * C_;
      s_off[tid][1] = base + (y0  * W_ + x1i) * C_;
      s_off[tid][2] = base + (y1i * W_ + x0 ) * C_;
      s_off[tid][3] = base + (y1i * W_ + x1i) * C_;
      s_w[tid][0] = (1.f - ly) * (1.f - lx);
      s_w[tid][1] = (1.f - ly) * lx;
      s_w[tid][2] = ly * (1.f - lx);
      s_w[tid][3] = ly * lx;
    }
    __syncthreads();
    {
      int rr = tid >> 5;
      int c0 = (tid & 31) * 8;
      float acc[8] = {};
#pragma unroll
      for (int s = 0; s < 4; ++s) {
        int e = rr * 4 + s;
#pragma unroll
        for (int q = 0; q < 4; ++q) {
          int off = s_off[e][q];
          float w = s_w[e][q];
          f16x8 v = *(const f16x8*)(fT + off + c0);
#pragma unroll
          for (int k = 0; k < 8; ++k) acc[k] += w * (float)v[k];
        }
      }
#pragma unroll
      for (int k = 0; k < 8; ++k) sv[rr][c0 + k] = acc[k] * 0.25f;
    }
    __syncthreads();
    int c = tid;
    int kt = c >> 5;
    int l5 = c & 31;
    int quad = l5 >> 3;
    int r8 = l5 & 7;
    int lane = quad * 16 + pass * 8 + r8;
    int cbase = kt * 32 + quad * 8;
    f16x8 hv;
#pragma unroll
    for (int jj = 0; jj < 8; ++jj) hv[jj] = (f16)sv[r8][cbase + jj];
    size_t off = ((size_t)(mt * KT1 + bin * 8 + kt) * 64 + lane) * 8;
    *(f16x8*)(Ahi + off) = hv;
    __syncthreads();
  }
}

// ---------------------------------------------------------------------------
// K3: fc1_w -> fp16 fragment-linear (row-permute). v[8] prefetch keeps 8
// loads in flight before LDS writes.
// ---------------------------------------------------------------------------
__global__ __launch_bounds__(256) void k_convw1(const float* __restrict__ src,
                                                f16* __restrict__ dst) {
  __shared__ float tile[32][65];
  int kt = blockIdx.x, ng = blockIdx.y;
  int t = threadIdx.x;
  int n0 = ng * 64;
  int col = t & 63;
  float vv[8];
#pragma unroll
  for (int p = 0; p < 8; ++p) {
    int k = kt * 32 + p * 4 + (t >> 6);
    int row = (k & 255) * 49 + (k >> 8);
    vv[p] = src[(size_t)row * 1024 + n0 + col];
  }
#pragma unroll
  for (int p = 0; p < 8; ++p) tile[p * 4 + (t >> 6)][col] = vv[p];
  __syncthreads();
  int sub = t >> 6, lane = t & 63;
  int nt = ng * 4 + sub;
  int nl = lane & 15, kg = lane >> 4;
  f16x8 h;
#pragma unroll
  for (int e = 0; e < 8; ++e)
    h[e] = (f16)tile[kg * 8 + e][sub * 16 + nl];
  *(f16x8*)(dst + ((size_t)(nt * KT1 + kt) * 64 + lane) * 8) = h;
}

// ---------------------------------------------------------------------------
// K4: MFMA GEMM, BK=64 (2 k-tiles per barrier, 32 KB LDS). BM=BN=128,
// 4 waves (2x2) each 64x64. Requires even ktPerSplit.
// ---------------------------------------------------------------------------
__global__ __launch_bounds__(256, 2) void k_gemm_mfma(
    const f16* __restrict__ Ahi, const f16* __restrict__ Bw,
    float* __restrict__ P, int N, int KTtot, int ktPerSplit) {
  __shared__ f16 sA[16 * 512];
  __shared__ f16 sB[16 * 512];
  int tid = threadIdx.x;
  int lane = tid & 63, w = tid >> 6;
  int wm = w >> 1, wn = w & 1;
  int bn = blockIdx.x, bm = blockIdx.y, z = blockIdx.z;
  int kt0 = z * ktPerSplit, ktEnd = kt0 + ktPerSplit;

  f32x4 acc[4][4];
#pragma unroll
  for (int i = 0; i < 4; ++i)
#pragma unroll
    for (int j = 0; j < 4; ++j) {
      f32x4 zv = {0.f, 0.f, 0.f, 0.f};
      acc[i][j] = zv;
    }

  for (int kt = kt0; kt + 1 < ktEnd; kt += 2) {
#pragma unroll
    for (int tt = 0; tt < 8; ++tt) {
      int t = 8 * w + tt;          // 0..31
      int k2 = t >> 4;
      int tl = t & 15;
      const f16* g;
      f16* l;
      if (tl < 8) { g = Ahi + ((size_t)(bm*8 + tl)     * KTtot + kt + k2) * 512; l = sA + (k2*8 + tl) * 512; }
      else        { g = Bw  + ((size_t)(bn*8 + tl - 8) * KTtot + kt + k2) * 512; l = sB + (k2*8 + tl - 8) * 512; }
      tile_load16(g + lane * 8, l);
    }
    __syncthreads();
#pragma unroll
    for (int k2 = 0; k2 < 2; ++k2) {
      f16x8 ah[4], bw[4];
#pragma unroll
      for (int i = 0; i < 4; ++i) {
        ah[i] = *(const f16x8*)(sA + (k2*8 + wm*4 + i) * 512 + lane * 8);
        bw[i] = *(const f16x8*)(sB + (k2*8 + wn*4 + i) * 512 + lane * 8);
      }
#pragma unroll
      for (int i = 0; i < 4; ++i)
#pragma unroll
        for (int j = 0; j < 4; ++j)
          acc[i][j] = __builtin_amdgcn_mfma_f32_16x16x32_f16(ah[i], bw[j], acc[i][j], 0, 0, 0);
    }
    __syncthreads();
  }

  int quad = lane >> 4, cl = lane & 15;
  float* Pz = P + (size_t)z * 1024 * (size_t)N;
#pragma unroll
  for (int i = 0; i < 4; ++i) {
    int row = bm * 128 + wm * 64 + i * 16 + quad * 4;
#pragma unroll
    for (int j = 0; j < 4; ++j) {
      int col = bn * 128 + wn * 64 + j * 16 + cl;
#pragma unroll
      for (int r = 0; r < 4; ++r)
        Pz[(size_t)(row + r) * N + col] = acc[i][j][r];
    }
  }
}

// ---------------------------------------------------------------------------
// K_MID: fused (a) split-K reduce + bias + relu -> A frag-linear
// [blocks 0..511], (b) next weight -> frag-linear [blocks 512..]. wmode 0:
// direct ld=1024 (512 blocks); wmode 2: concat cls|box pad-512 (256 blocks).
// ---------------------------------------------------------------------------
__global__ __launch_bounds__(256) void k_mid(
    const float* __restrict__ P, const float* __restrict__ bias,
    f16* __restrict__ Adst, int nsplit,
    const float* __restrict__ wsrc, const float* __restrict__ wsrc2,
    f16* __restrict__ Wdst, int wmode) {
  __shared__ float tile[32][65];
  int bid = blockIdx.x;
  int t = threadIdx.x;
  if (bid < 512) {
    int q = bid * 256 + t;
    int lane = q & 63, tl = q >> 6;
    int mt = tl >> 5, kt = tl & 31;
    int m  = mt * 16 + (lane & 15);
    int n0 = kt * 32 + (lane >> 4) * 8;
    float v[8];
#pragma unroll
    for (int jj = 0; jj < 8; ++jj) v[jj] = bias[n0 + jj];
    for (int s = 0; s < nsplit; ++s) {
      const float* p = P + (size_t)s * 1048576 + (size_t)m * 1024 + n0;
#pragma unroll
      for (int jj = 0; jj < 8; ++jj) v[jj] += p[jj];
    }
    f16x8 hv;
#pragma unroll
    for (int jj = 0; jj < 8; ++jj) hv[jj] = (f16)fmaxf(v[jj], 0.f);
    *(f16x8*)(Adst + (size_t)q * 8) = hv;
  } else {
    int cb = bid - 512;
    int kt = cb & 31, ng = cb >> 5;
    int n0 = ng * 64;
    int col = t & 63;
    float vv[8];
#pragma unroll
    for (int p = 0; p < 8; ++p) {
      int k = kt * 32 + p * 4 + (t >> 6);
      if (wmode == 0) {
        vv[p] = wsrc[(size_t)k * 1024 + n0 + col];
      } else {
        int n = n0 + col;
        vv[p] = (n < 81) ? wsrc[(size_t)k * 81 + n]
                         : ((n < 401) ? wsrc2[(size_t)k * 320 + (n - 81)] : 0.f);
      }
    }
#pragma unroll
    for (int p = 0; p < 8; ++p) tile[p * 4 + (t >> 6)][col] = vv[p];
    __syncthreads();
    int sub = t >> 6, lane = t & 63;
    int nt = ng * 4 + sub;
    int nl = lane & 15, kg = lane >> 4;
    f16x8 h;
#pragma unroll
    for (int e = 0; e < 8; ++e)
      h[e] = (f16)tile[kg * 8 + e][sub * 16 + nl];
    *(f16x8*)(Wdst + ((size_t)(nt * 32 + kt) * 64 + lane) * 8) = h;
  }
}

// ---------------------------------------------------------------------------
// K6: heads split-K reduce + concat bias -> out (1024 x 401 fp32)
// ---------------------------------------------------------------------------
__global__ __launch_bounds__(256) void k_out(const float* __restrict__ P,
                                             const float* __restrict__ cls_b,
                                             const float* __restrict__ box_b,
                                             float* __restrict__ out, int nsplit) {
  int idx = blockIdx.x * 256 + threadIdx.x;
  if (idx >= RTOT * OUTC) return;
  int m = idx / OUTC, n = idx - m * OUTC;
  float v = (n < 81) ? cls_b[n] : box_b[n - 81];
  for (int s = 0; s < nsplit; ++s)
    v += P[(size_t)s * (1024 * 512) + (size_t)m * 512 + n];
  out[idx] = v;
}

// ---------------------------------------------------------------------------
extern "C" void kernel_launch(void* const* d_in, const int* in_sizes, int n_in,
                              void* d_out, int out_size, void* d_ws, size_t ws_size,
                              hipStream_t stream) {
  const float* features = (const float*)d_in[0];
  const float* prop     = (const float*)d_in[1];
  const float* gt       = (const float*)d_in[2];
  const float* rnd      = (const float*)d_in[4];
  const float* fc1_w    = (const float*)d_in[5];
  const float* fc1_b    = (const float*)d_in[6];
  const float* fc2_w    = (const float*)d_in[7];
  const float* fc2_b    = (const float*)d_in[8];
  const float* cls_w    = (const float*)d_in[9];
  const float* cls_b    = (const float*)d_in[10];
  const float* box_w    = (const float*)d_in[11];
  const float* box_b    = (const float*)d_in[12];
  float* out = (float*)d_out;

  char* base = (char*)d_ws;
  f16*   fT   = (f16*)(base + 0);                      //  4,194,304 B (8 MB slot)
  float* rois = (float*)(base + 8388608);              //     16,384 B
  char*  p2   = base + 8404992;
  f16* A1hi = (f16*)(base + 8404992);                  // 25,690,112 B
  f16* W1   = (f16*)(base + 34095104);                 // 25,690,112 B
  float* P1 = (float*)(base + 59785216);               // s1 * 4,194,304 B
  int s1 = (ws_size >= (size_t)59785216 + 14ull * 4194304) ? 14 : 8;
  // phase-2 overlays (used only after FC1 GEMM) — reuse A1hi/W1 region
  f16* A2hi = (f16*)(p2 + 0);          // 2,097,152
  f16* W2   = (f16*)(p2 + 2097152);    // 2,097,152
  f16* A3hi = (f16*)(p2 + 4194304);    // 2,097,152
  f16* W3   = (f16*)(p2 + 6291456);    // 1,048,576
  float* P2 = (float*)(p2 + 7340032);  // 16,777,216 (4 splits)
  float* P3 = (float*)(p2 + 24117248); //  8,388,608 (4 splits)
  // selection scratch: overlays P1 region (read before FC1 GEMM writes it)
  unsigned char* g_fg  = (unsigned char*)(base + 59785216);
  unsigned char* g_sel = (unsigned char*)(base + 59785216 + 4160);
  int*           g_cnt = (int*)(base + 59785216 + 8320);

  // fused transpose + iou (1026 blocks)
  k_tiou<<<dim3(1026), dim3(256), 0, stream>>>(features, prop, gt, fT,
                                               g_fg, g_cnt);
  k_rank<<<dim3((NB_ + 255) / 256, B_), dim3(256), 0, stream>>>(rnd, g_fg, g_cnt, g_sel);
  k_place<<<dim3(B_), dim3(64), 0, stream>>>(prop, gt, g_cnt, g_sel, rois);
  k_roialign<<<dim3(64, 49), dim3(256), 0, stream>>>(fT, rois, A1hi);
  k_convw1<<<dim3(KT1, 16), dim3(256), 0, stream>>>(fc1_w, W1);
  // FC1: 1024 x 12544 x 1024, split-K s1 (28 kt/split, even)
  k_gemm_mfma<<<dim3(8, 8, s1), dim3(256), 0, stream>>>(A1hi, W1, P1,
                                                        1024, KT1, KT1 / s1);
  // combine1 (512) + convw2 (512)
  k_mid<<<dim3(1024), dim3(256), 0, stream>>>(P1, fc1_b, A2hi, s1,
                                              fc2_w, nullptr, W2, 0);
  // FC2: 1024 x 1024 x 1024, split-K 4 (8 kt/split, even)
  k_gemm_mfma<<<dim3(8, 8, 4), dim3(256), 0, stream>>>(A2hi, W2, P2,
                                                       1024, KT2, KT2 / 4);
  // combine2 (512) + convw3 (256)
  k_mid<<<dim3(768), dim3(256), 0, stream>>>(P2, fc2_b, A3hi, 4,
                                             cls_w, box_w, W3, 2);
  // heads: 1024 x 1024 x 512(padded 401), split-K 4 (8 kt/split, even)
  k_gemm_mfma<<<dim3(4, 8, 4), dim3(256), 0, stream>>>(A3hi, W3, P3,
                                                       512, KT2, KT2 / 4);
  k_out<<<dim3((RTOT * OUTC + 255) / 256), dim3(256), 0, stream>>>(
      P3, cls_b, box_b, out, 4);
}

// Round 11
// 310.454 us; speedup vs baseline: 1.1629x; 1.1629x over previous
//
#include <hip/hip_runtime.h>
#include <cstdint>
#include <cstddef>

// ---- problem constants ----
constexpr int B_   = 2;
constexpr int N_   = 2000;
constexpr int M_   = 64;
constexpr int NB_  = N_ + M_;       // 2064
constexpr int C_   = 256;
constexpr int H_   = 64;
constexpr int W_   = 64;
constexpr int RPI  = 512;
constexpr int RTOT = B_ * RPI;      // 1024
constexpr int FG_CAP_ = 128;
constexpr int D_   = C_ * 49;       // 12544
constexpr int FC_  = 1024;
constexpr int OUTC = 401;           // 81 + 320
constexpr int KT1  = D_ / 32;       // 392 k-tiles for FC1
constexpr int KT2  = FC_ / 32;      // 32 k-tiles for FC2/heads
constexpr float IOU_T = 0.5f;

// RULE (r6, r10 post-mortems): do NOT fuse front-of-stream kernels into
// branchy multi-role kernels — register budget collapses (VGPR 16/20) and
// the dispatch window contends with the harness's 256MB re-poison fills.

typedef _Float16 f16;
typedef f16   f16x2 __attribute__((ext_vector_type(2)));
typedef f16   f16x8 __attribute__((ext_vector_type(8)));
typedef float f32x4 __attribute__((ext_vector_type(4)));

__device__ __forceinline__ void tile_load16(const void* g, void* l) {
  __builtin_amdgcn_global_load_lds(
      (const __attribute__((address_space(1))) unsigned int*)g,
      (__attribute__((address_space(3))) unsigned int*)l, 16, 0, 0);
}

// ---------------------------------------------------------------------------
// K0: features (B,C,H,W) -> f16 (B,H*W,C). 64-channel tile, f16x2 128B-line
// coalesced stores. (r9-verified fast standalone.)
// ---------------------------------------------------------------------------
__global__ __launch_bounds__(256) void k_transpose(const float* __restrict__ in,
                                                   f16* __restrict__ out) {
  __shared__ float tile[64][33];
  int b = blockIdx.z, hw0 = blockIdx.x * 32, c0 = blockIdx.y * 64;
  int t = threadIdx.x;
  int tx = t & 31, cr0 = t >> 5;
#pragma unroll
  for (int i = 0; i < 8; ++i) {
    int cr = cr0 + i * 8;
    tile[cr][tx] = in[((size_t)b * C_ + c0 + cr) * (H_ * W_) + hw0 + tx];
  }
  __syncthreads();
  int c2 = (t & 31) * 2, hr0 = t >> 5;
#pragma unroll
  for (int p = 0; p < 4; ++p) {
    int hr = hr0 + p * 8;
    f16x2 v;
    v[0] = (f16)tile[c2][hr];
    v[1] = (f16)tile[c2 + 1][hr];
    *(f16x2*)(out + ((size_t)b * (H_ * W_) + hw0 + hr) * C_ + c0 + c2) = v;
  }
}

// ---------------------------------------------------------------------------
// S1: IoU match -> fg flags + fg count. One block (1024 thr) per image.
// ---------------------------------------------------------------------------
__global__ __launch_bounds__(1024) void k_iou(const float* __restrict__ prop,
                                              const float* __restrict__ gt,
                                              unsigned char* __restrict__ fg,
                                              int* __restrict__ cnt) {
  __shared__ float s_gt[M_ * 4];
  __shared__ float s_area[M_];
  __shared__ int s_cnt;
  int b = blockIdx.x, t = threadIdx.x;
  if (t == 0) s_cnt = 0;
  if (t < M_ * 4) s_gt[t] = gt[(size_t)b * M_ * 4 + t];
  __syncthreads();
  if (t < M_) {
    float x1 = s_gt[t*4], y1 = s_gt[t*4+1], x2 = s_gt[t*4+2], y2 = s_gt[t*4+3];
    s_area[t] = (x2 - x1) * (y2 - y1);
  }
  __syncthreads();
  int local = 0;
  for (int j = t; j < NB_; j += 1024) {
    float bx1, by1, bx2, by2;
    if (j < N_) {
      const float* p = prop + ((size_t)b * N_ + j) * 4;
      bx1 = p[0]; by1 = p[1]; bx2 = p[2]; by2 = p[3];
    } else {
      const float* p = s_gt + (j - N_) * 4;
      bx1 = p[0]; by1 = p[1]; bx2 = p[2]; by2 = p[3];
    }
    float area_p = (bx2 - bx1) * (by2 - by1);
    float best = 0.f;
    for (int g = 0; g < M_; ++g) {
      float lx = fmaxf(s_gt[g*4], bx1),   lyv = fmaxf(s_gt[g*4+1], by1);
      float rx = fminf(s_gt[g*4+2], bx2), ry  = fminf(s_gt[g*4+3], by2);
      float w = fmaxf(rx - lx, 0.f), h = fmaxf(ry - lyv, 0.f);
      float inter = w * h;
      float iou = inter > 0.f ? inter / (s_area[g] + area_p - inter) : 0.f;
      best = fmaxf(best, iou);
    }
    int f = (best >= IOU_T) ? 1 : 0;
    fg[(size_t)b * NB_ + j] = (unsigned char)f;
    local += f;
  }
  atomicAdd(&s_cnt, local);
  __syncthreads();
  if (t == 0) cnt[b] = s_cnt;
}

// ---------------------------------------------------------------------------
// S2: branchless rank via combined u64 key (exact JAX stable tie-break).
// ---------------------------------------------------------------------------
__global__ __launch_bounds__(256) void k_rank(const float* __restrict__ rnd,
                                              const unsigned char* __restrict__ fg,
                                              const int* __restrict__ cnt,
                                              unsigned char* __restrict__ sel) {
  __shared__ unsigned long long s_key[NB_];
  int b = blockIdx.y, t = threadIdx.x;
  for (int j = t; j < NB_; j += 256) {
    float r = rnd[(size_t)b * NB_ + j];
    int f = (int)fg[(size_t)b * NB_ + j];
    float ck = r + 2.0f * (float)f;
    unsigned int ib = __float_as_uint(ck);
    s_key[j] = ((unsigned long long)ib << 11) | (unsigned int)j;
  }
  __syncthreads();
  int j = blockIdx.x * 256 + t;
  int jj = (j < NB_) ? j : 0;
  unsigned long long uj = s_key[jj];
  int rank_all = 0;
  const uint4* kp = (const uint4*)s_key;
#pragma unroll 4
  for (int k2 = 0; k2 < NB_ / 2; ++k2) {
    uint4 v = kp[k2];
    unsigned long long k0 = ((unsigned long long)v.y << 32) | v.x;
    unsigned long long k1 = ((unsigned long long)v.w << 32) | v.z;
    rank_all += (k0 < uj) ? 1 : 0;
    rank_all += (k1 < uj) ? 1 : 0;
  }
  if (j >= NB_) return;
  int fgcnt  = cnt[b];
  int num_fg = min(fgcnt, FG_CAP_);
  int num_bg = min(RPI - num_fg, NB_ - fgcnt);
  int myfg   = (uj >> 11) >= 0x40000000ull ? 1 : 0;
  int rank   = rank_all - (myfg ? (NB_ - fgcnt) : 0);
  int lim    = myfg ? num_fg : num_bg;
  sel[(size_t)b * NB_ + j] =
      (rank < lim) ? (unsigned char)(myfg ? 2 : 1) : (unsigned char)0;
}

// ---------------------------------------------------------------------------
// S3: lax.top_k placement via ballot prefix scan. One wave per image.
// ---------------------------------------------------------------------------
__global__ __launch_bounds__(64) void k_place(const float* __restrict__ prop,
                                              const float* __restrict__ gt,
                                              const int* __restrict__ cnt,
                                              const unsigned char* __restrict__ sel,
                                              float* __restrict__ rois) {
  int b = blockIdx.x, L = threadIdx.x;
  int fgcnt  = cnt[b];
  int num_fg = min(fgcnt, FG_CAP_);
  int num_bg = min(RPI - num_fg, NB_ - fgcnt);
  int S = num_fg + num_bg;
  int t2 = 0, t1 = 0, t0 = 0;
  unsigned long long lt = (L == 0) ? 0ull : ((~0ull) >> (64 - L));
  for (int c = 0; c < (NB_ + 63) / 64; ++c) {
    int j = c * 64 + L;
    int s = (j < NB_) ? (int)sel[(size_t)b * NB_ + j] : -1;
    unsigned long long m2 = __ballot(s == 2);
    unsigned long long m1 = __ballot(s == 1);
    unsigned long long m0 = __ballot(s == 0);
    int pos = -1;
    if (s == 2) {
      pos = t2 + __popcll(m2 & lt);
    } else if (s == 1) {
      pos = num_fg + t1 + __popcll(m1 & lt);
    } else if (s == 0) {
      int p0 = t0 + __popcll(m0 & lt);
      if (S + p0 < RPI) pos = S + p0;
    }
    if (pos >= 0) {
      const float* p = (j < N_) ? (prop + ((size_t)b * N_ + j) * 4)
                                : (gt + ((size_t)b * M_ + (j - N_)) * 4);
      float* o = rois + ((size_t)b * RPI + pos) * 4;
      o[0] = p[0]; o[1] = p[1]; o[2] = p[2]; o[3] = p[3];
    }
    t2 += __popcll(m2); t1 += __popcll(m1); t0 += __popcll(m0);
  }
}

// ---------------------------------------------------------------------------
// K2: ROI align (f16 features) -> A1 fp16 fragment-linear. f16x8 loads,
// LDS metadata, XCD-local grid (mt fastest).
// ---------------------------------------------------------------------------
__global__ __launch_bounds__(256) void k_roialign(const f16* __restrict__ fT,
                                                  const float* __restrict__ rois,
                                                  f16* __restrict__ Ahi) {
  __shared__ float sv[8][260];
  __shared__ int   s_off[32][4];
  __shared__ float s_w[32][4];
  int mt = blockIdx.x, bin = blockIdx.y;
  int tid = threadIdx.x;
  int by = bin / 7, bx = bin % 7;
  for (int pass = 0; pass < 2; ++pass) {
    if (tid < 32) {
      int rr = tid >> 2, s = tid & 3;
      int r = mt * 16 + pass * 8 + rr;
      const float* rp = rois + (size_t)r * 4;
      float x1 = rp[0] * 0.0625f - 0.5f;
      float y1 = rp[1] * 0.0625f - 0.5f;
      float x2 = rp[2] * 0.0625f - 0.5f;
      float y2 = rp[3] * 0.0625f - 0.5f;
      float stx = (x2 - x1) * (1.0f / 7.0f);
      float sty = (y2 - y1) * (1.0f / 7.0f);
      int oy = s >> 1, ox = s & 1;
      float xs = x1 + ((float)(2 * bx + ox) + 0.5f) * 0.5f * stx;
      float ys = y1 + ((float)(2 * by + oy) + 0.5f) * 0.5f * sty;
      xs = fminf(fmaxf(xs, 0.f), (float)(W_ - 1));
      ys = fminf(fmaxf(ys, 0.f), (float)(H_ - 1));
      int x0 = (int)floorf(xs), y0 = (int)floorf(ys);
      int x1i = min(x0 + 1, W_ - 1), y1i = min(y0 + 1, H_ - 1);
      float lx = xs - (float)x0, ly = ys - (float)y0;
      int base = (r >> 9) * (H_ * W_ * C_);
      s_off[tid][0] = base + (y0  * W_ + x0 ) * C_;
      s_off[tid][1] = base + (y0  * W_ + x1i) * C_;
      s_off[tid][2] = base + (y1i * W_ + x0 ) * C_;
      s_off[tid][3] = base + (y1i * W_ + x1i) * C_;
      s_w[tid][0] = (1.f - ly) * (1.f - lx);
      s_w[tid][1] = (1.f - ly) * lx;
      s_w[tid][2] = ly * (1.f - lx);
      s_w[tid][3] = ly * lx;
    }
    __syncthreads();
    {
      int rr = tid >> 5;
      int c0 = (tid & 31) * 8;
      float acc[8] = {};
#pragma unroll
      for (int s = 0; s < 4; ++s) {
        int e = rr * 4 + s;
#pragma unroll
        for (int q = 0; q < 4; ++q) {
          int off = s_off[e][q];
          float w = s_w[e][q];
          f16x8 v = *(const f16x8*)(fT + off + c0);
#pragma unroll
          for (int k = 0; k < 8; ++k) acc[k] += w * (float)v[k];
        }
      }
#pragma unroll
      for (int k = 0; k < 8; ++k) sv[rr][c0 + k] = acc[k] * 0.25f;
    }
    __syncthreads();
    int c = tid;
    int kt = c >> 5;
    int l5 = c & 31;
    int quad = l5 >> 3;
    int r8 = l5 & 7;
    int lane = quad * 16 + pass * 8 + r8;
    int cbase = kt * 32 + quad * 8;
    f16x8 hv;
#pragma unroll
    for (int jj = 0; jj < 8; ++jj) hv[jj] = (f16)sv[r8][cbase + jj];
    size_t off = ((size_t)(mt * KT1 + bin * 8 + kt) * 64 + lane) * 8;
    *(f16x8*)(Ahi + off) = hv;
    __syncthreads();
  }
}

// ---------------------------------------------------------------------------
// K3: fc1_w -> fp16 fragment-linear (row-permute), v[8] load prefetch.
// ---------------------------------------------------------------------------
__global__ __launch_bounds__(256) void k_convw1(const float* __restrict__ src,
                                                f16* __restrict__ dst) {
  __shared__ float tile[32][65];
  int kt = blockIdx.x, ng = blockIdx.y;
  int t = threadIdx.x;
  int n0 = ng * 64;
  int col = t & 63;
  float vv[8];
#pragma unroll
  for (int p = 0; p < 8; ++p) {
    int k = kt * 32 + p * 4 + (t >> 6);
    int row = (k & 255) * 49 + (k >> 8);
    vv[p] = src[(size_t)row * 1024 + n0 + col];
  }
#pragma unroll
  for (int p = 0; p < 8; ++p) tile[p * 4 + (t >> 6)][col] = vv[p];
  __syncthreads();
  int sub = t >> 6, lane = t & 63;
  int nt = ng * 4 + sub;
  int nl = lane & 15, kg = lane >> 4;
  f16x8 h;
#pragma unroll
  for (int e = 0; e < 8; ++e)
    h[e] = (f16)tile[kg * 8 + e][sub * 16 + nl];
  *(f16x8*)(dst + ((size_t)(nt * KT1 + kt) * 64 + lane) * 8) = h;
}

// ---------------------------------------------------------------------------
// K4: MFMA GEMM, BK=64 (2 k-tiles per barrier, 32 KB LDS). BM=BN=128,
// 4 waves (2x2) each 64x64. Requires even ktPerSplit.
// ---------------------------------------------------------------------------
__global__ __launch_bounds__(256, 2) void k_gemm_mfma(
    const f16* __restrict__ Ahi, const f16* __restrict__ Bw,
    float* __restrict__ P, int N, int KTtot, int ktPerSplit) {
  __shared__ f16 sA[16 * 512];
  __shared__ f16 sB[16 * 512];
  int tid = threadIdx.x;
  int lane = tid & 63, w = tid >> 6;
  int wm = w >> 1, wn = w & 1;
  int bn = blockIdx.x, bm = blockIdx.y, z = blockIdx.z;
  int kt0 = z * ktPerSplit, ktEnd = kt0 + ktPerSplit;

  f32x4 acc[4][4];
#pragma unroll
  for (int i = 0; i < 4; ++i)
#pragma unroll
    for (int j = 0; j < 4; ++j) {
      f32x4 zv = {0.f, 0.f, 0.f, 0.f};
      acc[i][j] = zv;
    }

  for (int kt = kt0; kt + 1 < ktEnd; kt += 2) {
#pragma unroll
    for (int tt = 0; tt < 8; ++tt) {
      int t = 8 * w + tt;          // 0..31
      int k2 = t >> 4;
      int tl = t & 15;
      const f16* g;
      f16* l;
      if (tl < 8) { g = Ahi + ((size_t)(bm*8 + tl)     * KTtot + kt + k2) * 512; l = sA + (k2*8 + tl) * 512; }
      else        { g = Bw  + ((size_t)(bn*8 + tl - 8) * KTtot + kt + k2) * 512; l = sB + (k2*8 + tl - 8) * 512; }
      tile_load16(g + lane * 8, l);
    }
    __syncthreads();
#pragma unroll
    for (int k2 = 0; k2 < 2; ++k2) {
      f16x8 ah[4], bw[4];
#pragma unroll
      for (int i = 0; i < 4; ++i) {
        ah[i] = *(const f16x8*)(sA + (k2*8 + wm*4 + i) * 512 + lane * 8);
        bw[i] = *(const f16x8*)(sB + (k2*8 + wn*4 + i) * 512 + lane * 8);
      }
#pragma unroll
      for (int i = 0; i < 4; ++i)
#pragma unroll
        for (int j = 0; j < 4; ++j)
          acc[i][j] = __builtin_amdgcn_mfma_f32_16x16x32_f16(ah[i], bw[j], acc[i][j], 0, 0, 0);
    }
    __syncthreads();
  }

  int quad = lane >> 4, cl = lane & 15;
  float* Pz = P + (size_t)z * 1024 * (size_t)N;
#pragma unroll
  for (int i = 0; i < 4; ++i) {
    int row = bm * 128 + wm * 64 + i * 16 + quad * 4;
#pragma unroll
    for (int j = 0; j < 4; ++j) {
      int col = bn * 128 + wn * 64 + j * 16 + cl;
#pragma unroll
      for (int r = 0; r < 4; ++r)
        Pz[(size_t)(row + r) * N + col] = acc[i][j][r];
    }
  }
}

// ---------------------------------------------------------------------------
// K_MID: fused (a) split-K reduce + bias + relu -> A frag-linear
// [blocks 0..511], (b) next weight -> frag-linear [blocks 512..]. Both
// branches pure streaming with v[8] prefetch (post-fill-window, measured
// neutral-positive r6/r10).
// ---------------------------------------------------------------------------
__global__ __launch_bounds__(256) void k_mid(
    const float* __restrict__ P, const float* __restrict__ bias,
    f16* __restrict__ Adst, int nsplit,
    const float* __restrict__ wsrc, const float* __restrict__ wsrc2,
    f16* __restrict__ Wdst, int wmode) {
  __shared__ float tile[32][65];
  int bid = blockIdx.x;
  int t = threadIdx.x;
  if (bid < 512) {
    int q = bid * 256 + t;
    int lane = q & 63, tl = q >> 6;
    int mt = tl >> 5, kt = tl & 31;
    int m  = mt * 16 + (lane & 15);
    int n0 = kt * 32 + (lane >> 4) * 8;
    float v[8];
#pragma unroll
    for (int jj = 0; jj < 8; ++jj) v[jj] = bias[n0 + jj];
    for (int s = 0; s < nsplit; ++s) {
      const float* p = P + (size_t)s * 1048576 + (size_t)m * 1024 + n0;
#pragma unroll
      for (int jj = 0; jj < 8; ++jj) v[jj] += p[jj];
    }
    f16x8 hv;
#pragma unroll
    for (int jj = 0; jj < 8; ++jj) hv[jj] = (f16)fmaxf(v[jj], 0.f);
    *(f16x8*)(Adst + (size_t)q * 8) = hv;
  } else {
    int cb = bid - 512;
    int kt = cb & 31, ng = cb >> 5;
    int n0 = ng * 64;
    int col = t & 63;
    float vv[8];
#pragma unroll
    for (int p = 0; p < 8; ++p) {
      int k = kt * 32 + p * 4 + (t >> 6);
      if (wmode == 0) {
        vv[p] = wsrc[(size_t)k * 1024 + n0 + col];
      } else {
        int n = n0 + col;
        vv[p] = (n < 81) ? wsrc[(size_t)k * 81 + n]
                         : ((n < 401) ? wsrc2[(size_t)k * 320 + (n - 81)] : 0.f);
      }
    }
#pragma unroll
    for (int p = 0; p < 8; ++p) tile[p * 4 + (t >> 6)][col] = vv[p];
    __syncthreads();
    int sub = t >> 6, lane = t & 63;
    int nt = ng * 4 + sub;
    int nl = lane & 15, kg = lane >> 4;
    f16x8 h;
#pragma unroll
    for (int e = 0; e < 8; ++e)
      h[e] = (f16)tile[kg * 8 + e][sub * 16 + nl];
    *(f16x8*)(Wdst + ((size_t)(nt * 32 + kt) * 64 + lane) * 8) = h;
  }
}

// ---------------------------------------------------------------------------
// K6: heads split-K reduce + concat bias -> out (1024 x 401 fp32)
// ---------------------------------------------------------------------------
__global__ __launch_bounds__(256) void k_out(const float* __restrict__ P,
                                             const float* __restrict__ cls_b,
                                             const float* __restrict__ box_b,
                                             float* __restrict__ out, int nsplit) {
  int idx = blockIdx.x * 256 + threadIdx.x;
  if (idx >= RTOT * OUTC) return;
  int m = idx / OUTC, n = idx - m * OUTC;
  float v = (n < 81) ? cls_b[n] : box_b[n - 81];
  for (int s = 0; s < nsplit; ++s)
    v += P[(size_t)s * (1024 * 512) + (size_t)m * 512 + n];
  out[idx] = v;
}

// ---------------------------------------------------------------------------
extern "C" void kernel_launch(void* const* d_in, const int* in_sizes, int n_in,
                              void* d_out, int out_size, void* d_ws, size_t ws_size,
                              hipStream_t stream) {
  const float* features = (const float*)d_in[0];
  const float* prop     = (const float*)d_in[1];
  const float* gt       = (const float*)d_in[2];
  const float* rnd      = (const float*)d_in[4];
  const float* fc1_w    = (const float*)d_in[5];
  const float* fc1_b    = (const float*)d_in[6];
  const float* fc2_w    = (const float*)d_in[7];
  const float* fc2_b    = (const float*)d_in[8];
  const float* cls_w    = (const float*)d_in[9];
  const float* cls_b    = (const float*)d_in[10];
  const float* box_w    = (const float*)d_in[11];
  const float* box_b    = (const float*)d_in[12];
  float* out = (float*)d_out;

  char* base = (char*)d_ws;
  f16*   fT   = (f16*)(base + 0);                      //  4,194,304 B (8 MB slot)
  float* rois = (float*)(base + 8388608);              //     16,384 B
  char*  p2   = base + 8404992;
  f16* A1hi = (f16*)(base + 8404992);                  // 25,690,112 B
  f16* W1   = (f16*)(base + 34095104);                 // 25,690,112 B
  float* P1 = (float*)(base + 59785216);               // s1 * 4,194,304 B
  int s1 = (ws_size >= (size_t)59785216 + 14ull * 4194304) ? 14 : 8;
  // phase-2 overlays (used only after FC1 GEMM) — reuse A1hi/W1 region
  f16* A2hi = (f16*)(p2 + 0);          // 2,097,152
  f16* W2   = (f16*)(p2 + 2097152);    // 2,097,152
  f16* A3hi = (f16*)(p2 + 4194304);    // 2,097,152
  f16* W3   = (f16*)(p2 + 6291456);    // 1,048,576
  float* P2 = (float*)(p2 + 7340032);  // 16,777,216 (4 splits)
  float* P3 = (float*)(p2 + 24117248); //  8,388,608 (4 splits)
  // selection scratch: overlays P1 region (read before FC1 GEMM writes it)
  unsigned char* g_fg  = (unsigned char*)(base + 59785216);
  unsigned char* g_sel = (unsigned char*)(base + 59785216 + 4160);
  int*           g_cnt = (int*)(base + 59785216 + 8320);

  k_transpose<<<dim3(128, 4, B_), dim3(256), 0, stream>>>(features, fT);
  k_iou<<<dim3(B_), dim3(1024), 0, stream>>>(prop, gt, g_fg, g_cnt);
  k_rank<<<dim3((NB_ + 255) / 256, B_), dim3(256), 0, stream>>>(rnd, g_fg, g_cnt, g_sel);
  k_place<<<dim3(B_), dim3(64), 0, stream>>>(prop, gt, g_cnt, g_sel, rois);
  k_roialign<<<dim3(64, 49), dim3(256), 0, stream>>>(fT, rois, A1hi);
  k_convw1<<<dim3(KT1, 16), dim3(256), 0, stream>>>(fc1_w, W1);
  // FC1: 1024 x 12544 x 1024, split-K s1=14 (28 kt/split, even)
  k_gemm_mfma<<<dim3(8, 8, s1), dim3(256), 0, stream>>>(A1hi, W1, P1,
                                                        1024, KT1, KT1 / s1);
  // combine1 (512) + convw2 (512)
  k_mid<<<dim3(1024), dim3(256), 0, stream>>>(P1, fc1_b, A2hi, s1,
                                              fc2_w, nullptr, W2, 0);
  // FC2: 1024 x 1024 x 1024, split-K 4 (8 kt/split, even)
  k_gemm_mfma<<<dim3(8, 8, 4), dim3(256), 0, stream>>>(A2hi, W2, P2,
                                                       1024, KT2, KT2 / 4);
  // combine2 (512) + convw3 (256)
  k_mid<<<dim3(768), dim3(256), 0, stream>>>(P2, fc2_b, A3hi, 4,
                                             cls_w, box_w, W3, 2);
  // heads: 1024 x 1024 x 512(padded 401), split-K 4 (8 kt/split, even)
  k_gemm_mfma<<<dim3(4, 8, 4), dim3(256), 0, stream>>>(A3hi, W3, P3,
                                                       512, KT2, KT2 / 4);
  k_out<<<dim3((RTOT * OUTC + 255) / 256), dim3(256), 0, stream>>>(
      P3, cls_b, box_b, out, 4);
}